// Round 1
// 736.654 us; speedup vs baseline: 1.0312x; 1.0312x over previous
//
#include <hip/hip_runtime.h>
#include <math.h>

#define B_    32
#define R_    4
#define IN_   1024
#define OUT_  1024
#define S_    64                 // i-splits per b (r is folded into the block)
#define CHUNK (IN_ / S_)         // 16 i-iterations per block
#define NPRE  ((size_t)IN_ * OUT_ + OUT_)

#define C_HALF_LOG_2PI 0.9189385332046727f
#define INV_SQRT_2PI   0.3989422804014327f
#define INV_SQRT_2PI_S 3.9894228040143270f   // 1/(sqrt(2pi)*0.1)
#define LOG_MIN       -23.025850929940457f   // log(1e-10)
#define LOG_MAX        2.3025850929940460f   // log(10)

__device__ __forceinline__ float softplus_f(float x) {
    // stable: max(x,0) + log1p(exp(-|x|))
    return fmaxf(x, 0.0f) + log1pf(__expf(-fabsf(x)));
}

__global__ void init_kernel(float* __restrict__ out) {
    int idx = blockIdx.x * 256 + threadIdx.x;
    if (idx < B_ * OUT_ + 2) out[idx] = 0.0f;
}

// sigma precompute + output zero-init fused (saves one launch).
// lpb is no longer precomputed: lb = -C - log(sigma) is recomputed in-kernel
// once per (i,o) and reused across the 4 r's — ~2us of VALU vs 512MB of
// LLC re-read traffic.
__global__ void precomp_kernel(const float* __restrict__ ro,
                               const float* __restrict__ ro_bias,
                               float* __restrict__ sig,
                               float* __restrict__ out) {
    size_t idx = (size_t)blockIdx.x * 256 + threadIdx.x;
    if (idx < B_ * OUT_ + 2) out[idx] = 0.0f;
    if (idx >= NPRE) return;
    float rv = (idx < (size_t)IN_ * OUT_) ? ro[idx] : ro_bias[idx - (size_t)IN_ * OUT_];
    sig[idx] = softplus_f(rv);
}

// per-component fused update: einsum acc, log-mixture sum, log-gaussian sum
#define PROC(E, M, SG, LB, ACC)                                              \
    {                                                                        \
        float w  = fmaf((E), (SG), (M));                                     \
        (ACC)    = fmaf(xv, w, (ACC));                                       \
        float t  = -0.5f * w * w;                                            \
        float g1 = fmaxf(__expf(t)          * INV_SQRT_2PI,   1e-10f);       \
        float g2 = fmaxf(__expf(100.0f * t) * INV_SQRT_2PI_S, 1e-10f);       \
        smix += __logf(0.5f * (g1 + g2));                                    \
        float lw = fmaf((E) * (E), -0.5f, (LB));                             \
        slpw += fminf(fmaxf(lw, LOG_MIN), LOG_MAX);                          \
    }

template <bool USE_WS>
__global__ __launch_bounds__(256)
void main_kernel(const float* __restrict__ x,
                 const float* __restrict__ mu,
                 const float* __restrict__ ro,
                 const float* __restrict__ mu_bias,
                 const float* __restrict__ ro_bias,
                 const float* __restrict__ eps,
                 const float* __restrict__ eps_bias,
                 const float* __restrict__ sig_ws,
                 float* __restrict__ out) {
    const int tid = threadIdx.x;
    const int bid = blockIdx.x;
    const int s   = bid & (S_ - 1);
    const int b   = bid >> 6;
    const int i0  = s * CHUNK;

    __shared__ float xs[CHUNK];
    if (tid < CHUNK) xs[tid] = x[b * IN_ + i0 + tid];
    __syncthreads();

    const float4* mu4  = (const float4*)(mu + (size_t)i0 * OUT_) + tid;
    const float4* sig4 = USE_WS ? (const float4*)(sig_ws + (size_t)i0 * OUT_) + tid : nullptr;
    const float4* ro4  = USE_WS ? nullptr : (const float4*)(ro + (size_t)i0 * OUT_) + tid;

    // 4 eps rows (one per r) share this block's mu/sig chunk
    const float4* e4[R_];
#pragma unroll
    for (int r = 0; r < R_; ++r)
        e4[r] = (const float4*)(eps + ((size_t)(b * R_ + r) * IN_ + i0) * OUT_) + tid;

    float4 acc = {0.f, 0.f, 0.f, 0.f};
    float smix = 0.f, slpw = 0.f;

    for (int ii = 0; ii < CHUNK; ++ii) {
        const int stride = ii * (OUT_ / 4);
        const float xv = xs[ii];
        float4 m = mu4[stride];
        float4 sg, lb;
        if (USE_WS) {
            sg = sig4[stride];
        } else {
            float4 rr = ro4[stride];
            sg.x = softplus_f(rr.x);
            sg.y = softplus_f(rr.y);
            sg.z = softplus_f(rr.z);
            sg.w = softplus_f(rr.w);
        }
        lb.x = -C_HALF_LOG_2PI - __logf(sg.x);
        lb.y = -C_HALF_LOG_2PI - __logf(sg.y);
        lb.z = -C_HALF_LOG_2PI - __logf(sg.z);
        lb.w = -C_HALF_LOG_2PI - __logf(sg.w);
#pragma unroll
        for (int r = 0; r < R_; ++r) {
            float4 e = e4[r][stride];
            PROC(e.x, m.x, sg.x, lb.x, acc.x);
            PROC(e.y, m.y, sg.y, lb.y, acc.y);
            PROC(e.z, m.z, sg.z, lb.z, acc.z);
            PROC(e.w, m.w, sg.w, lb.w, acc.w);
        }
    }

    // bias handled once per b by the s==0 block (all 4 r's)
    if (s == 0) {
        float4 mb = ((const float4*)mu_bias)[tid];
        float4 sgb, lbb;
        if (USE_WS) {
            sgb = ((const float4*)(sig_ws + (size_t)IN_ * OUT_))[tid];
        } else {
            float4 rb = ((const float4*)ro_bias)[tid];
            sgb.x = softplus_f(rb.x);
            sgb.y = softplus_f(rb.y);
            sgb.z = softplus_f(rb.z);
            sgb.w = softplus_f(rb.w);
        }
        lbb.x = -C_HALF_LOG_2PI - __logf(sgb.x);
        lbb.y = -C_HALF_LOG_2PI - __logf(sgb.y);
        lbb.z = -C_HALF_LOG_2PI - __logf(sgb.z);
        lbb.w = -C_HALF_LOG_2PI - __logf(sgb.w);
        const float xv = 1.0f;   // acc += 1 * bias
#pragma unroll
        for (int r = 0; r < R_; ++r) {
            float4 eb = ((const float4*)(eps_bias + (size_t)(b * R_ + r) * OUT_))[tid];
            PROC(eb.x, mb.x, sgb.x, lbb.x, acc.x);
            PROC(eb.y, mb.y, sgb.y, lbb.y, acc.y);
            PROC(eb.z, mb.z, sgb.z, lbb.z, acc.z);
            PROC(eb.w, mb.w, sgb.w, lbb.w, acc.w);
        }
    }

    // out[b, o] += acc / R  (mean over r folded in-register; summed across s via atomics)
    float* outp = out + (size_t)b * OUT_ + tid * 4;
    atomicAdd(outp + 0, acc.x * 0.25f);
    atomicAdd(outp + 1, acc.y * 0.25f);
    atomicAdd(outp + 2, acc.z * 0.25f);
    atomicAdd(outp + 3, acc.w * 0.25f);

    // block-reduce the two scalar sums, then one atomic pair per block
    for (int off = 32; off > 0; off >>= 1) {
        smix += __shfl_down(smix, off, 64);
        slpw += __shfl_down(slpw, off, 64);
    }
    __shared__ float red[8];
    const int wave = tid >> 6, lane = tid & 63;
    if (lane == 0) { red[wave] = smix; red[4 + wave] = slpw; }
    __syncthreads();
    if (tid == 0) {
        float sm = red[0] + red[1] + red[2] + red[3];
        float sl = red[4] + red[5] + red[6] + red[7];
        atomicAdd(out + B_ * OUT_ + 0, sm * (1.0f / 128.0f));
        atomicAdd(out + B_ * OUT_ + 1, sl * (1.0f / 128.0f));
    }
}

extern "C" void kernel_launch(void* const* d_in, const int* in_sizes, int n_in,
                              void* d_out, int out_size, void* d_ws, size_t ws_size,
                              hipStream_t stream) {
    const float* x       = (const float*)d_in[0];
    const float* mu      = (const float*)d_in[1];
    const float* ro      = (const float*)d_in[2];
    const float* mu_bias = (const float*)d_in[3];
    const float* ro_bias = (const float*)d_in[4];
    const float* eps     = (const float*)d_in[5];
    const float* eps_b   = (const float*)d_in[6];
    float* out = (float*)d_out;

    const bool use_ws = ws_size >= NPRE * sizeof(float);
    float* sig_ws = (float*)d_ws;

    if (use_ws) {
        // precomp also zero-inits out (NPRE/256 = 4100 blocks covers B*OUT+2)
        precomp_kernel<<<(int)((NPRE + 255) / 256), 256, 0, stream>>>(ro, ro_bias, sig_ws, out);
        main_kernel<true><<<B_ * S_, 256, 0, stream>>>(
            x, mu, ro, mu_bias, ro_bias, eps, eps_b, sig_ws, out);
    } else {
        init_kernel<<<(B_ * OUT_ + 2 + 255) / 256, 256, 0, stream>>>(out);
        main_kernel<false><<<B_ * S_, 256, 0, stream>>>(
            x, mu, ro, mu_bias, ro_bias, eps, eps_b, nullptr, out);
    }
}

// Round 3
// 703.062 us; speedup vs baseline: 1.0805x; 1.0478x over previous
//
#include <hip/hip_runtime.h>
#include <math.h>

#define B_    32
#define R_    4
#define IN_   1024
#define OUT_  1024
#define S_    64                 // i-splits per b (r is folded into the block)
#define CHUNK (IN_ / S_)         // 16 i-iterations per block
#define NPRE  ((size_t)IN_ * OUT_ + OUT_)

// exp2/log2-domain constants: fold all scale factors into the FMA feeding
// native v_exp_f32 / v_log_f32 (which ARE exp2/log2 in hardware).
//   g1 = exp(-w^2/2)/sqrt(2pi)         = 2^(w2*A1M + A1B)
//   g2 = exp(-w^2/0.02)/(sqrt(2pi)*.1) = 2^(w2*A2M + A2B)
#define A1M  (-0.72134752f)      // -1/(2 ln2)
#define A1B  (-1.3257481f)       // log2(1/sqrt(2pi))  (== -C_half_log_2pi/ln2)
#define A2M  (-72.134752f)       // -50/ln2
#define A2B  ( 1.9961800f)       // log2(1/(sqrt(2pi)*0.1))
#define LO2  (-33.219281f)       // log2(1e-10)
#define HI2  ( 3.3219281f)       // log2(10)
#define LN2F ( 0.69314718f)

// native vector type for nontemporal builtins (HIP_vector_type is rejected)
typedef float f4 __attribute__((ext_vector_type(4)));

#if __has_builtin(__builtin_amdgcn_exp2f)
#define EXP2F(x) __builtin_amdgcn_exp2f(x)
#else
#define EXP2F(x) exp2f(x)
#endif
#if __has_builtin(__builtin_amdgcn_logf)
#define LOG2F(x) __builtin_amdgcn_logf(x)
#else
#define LOG2F(x) log2f(x)
#endif

__device__ __forceinline__ float softplus_f(float x) {
    // stable: max(x,0) + log1p(exp(-|x|))
    return fmaxf(x, 0.0f) + log1pf(__expf(-fabsf(x)));
}

__global__ void init_kernel(float* __restrict__ out) {
    int idx = blockIdx.x * 256 + threadIdx.x;
    if (idx < B_ * OUT_ + 2) out[idx] = 0.0f;
}

// sigma precompute + output zero-init fused (saves one launch).
__global__ void precomp_kernel(const float* __restrict__ ro,
                               const float* __restrict__ ro_bias,
                               float* __restrict__ sig,
                               float* __restrict__ out) {
    size_t idx = (size_t)blockIdx.x * 256 + threadIdx.x;
    if (idx < B_ * OUT_ + 2) out[idx] = 0.0f;
    if (idx >= NPRE) return;
    float rv = (idx < (size_t)IN_ * OUT_) ? ro[idx] : ro_bias[idx - (size_t)IN_ * OUT_];
    sig[idx] = softplus_f(rv);
}

// per-component fused update, log2 domain:
//   smix2 += log2(g1+g2)          [ln: sum(log(.5*(g1+g2))) = LN2*(smix2 - n)]
//   slpw2 += clamp(lb2 + e2*A1M, log2 1e-10, log2 10)       [ln: LN2*slpw2]
#define PROC(E, M, SG, LB2, ACC)                                             \
    {                                                                        \
        float w  = fmaf((E), (SG), (M));                                     \
        (ACC)    = fmaf(xv, w, (ACC));                                       \
        float w2 = w * w;                                                    \
        float g1 = fmaxf(EXP2F(fmaf(w2, A1M, A1B)), 1e-10f);                 \
        float g2 = fmaxf(EXP2F(fmaf(w2, A2M, A2B)), 1e-10f);                 \
        smix2 += LOG2F(g1 + g2);                                             \
        float lw2 = fmaf((E) * (E), A1M, (LB2));                             \
        slpw2 += fminf(fmaxf(lw2, LO2), HI2);                                \
    }

template <bool USE_WS>
__global__ __launch_bounds__(256)
void main_kernel(const float* __restrict__ x,
                 const float* __restrict__ mu,
                 const float* __restrict__ ro,
                 const float* __restrict__ mu_bias,
                 const float* __restrict__ ro_bias,
                 const float* __restrict__ eps,
                 const float* __restrict__ eps_bias,
                 const float* __restrict__ sig_ws,
                 float* __restrict__ out) {
    const int tid = threadIdx.x;
    const int bid = blockIdx.x;
    const int s   = bid & (S_ - 1);
    const int b   = bid >> 6;
    const int i0  = s * CHUNK;

    __shared__ float xs[CHUNK];
    if (tid < CHUNK) xs[tid] = x[b * IN_ + i0 + tid];
    __syncthreads();

    const float4* mu4  = (const float4*)(mu + (size_t)i0 * OUT_) + tid;
    const float4* sig4 = USE_WS ? (const float4*)(sig_ws + (size_t)i0 * OUT_) + tid : nullptr;
    const float4* ro4  = USE_WS ? nullptr : (const float4*)(ro + (size_t)i0 * OUT_) + tid;

    // 4 eps rows (one per r) share this block's mu/sig chunk
    const f4* e4[R_];
#pragma unroll
    for (int r = 0; r < R_; ++r)
        e4[r] = (const f4*)(eps + ((size_t)(b * R_ + r) * IN_ + i0) * OUT_) + tid;

    float4 acc = {0.f, 0.f, 0.f, 0.f};
    float smix2 = 0.f, slpw2 = 0.f;

    for (int ii = 0; ii < CHUNK; ++ii) {
        const int stride = ii * (OUT_ / 4);
        const float xv = xs[ii];
        float4 m = mu4[stride];
        float4 sg, lb;
        if (USE_WS) {
            sg = sig4[stride];
        } else {
            float4 rr = ro4[stride];
            sg.x = softplus_f(rr.x);
            sg.y = softplus_f(rr.y);
            sg.z = softplus_f(rr.z);
            sg.w = softplus_f(rr.w);
        }
        // lb2 = log2(1/sqrt(2pi)) - log2(sigma), shared across 4 r's
        lb.x = A1B - LOG2F(sg.x);
        lb.y = A1B - LOG2F(sg.y);
        lb.z = A1B - LOG2F(sg.z);
        lb.w = A1B - LOG2F(sg.w);
#pragma unroll
        for (int r = 0; r < R_; ++r) {
            // eps is a zero-reuse 537MB stream: non-temporal so it doesn't
            // evict the mu/sig working set from per-XCD L2
            f4 e = __builtin_nontemporal_load(&e4[r][stride]);
            PROC(e.x, m.x, sg.x, lb.x, acc.x);
            PROC(e.y, m.y, sg.y, lb.y, acc.y);
            PROC(e.z, m.z, sg.z, lb.z, acc.z);
            PROC(e.w, m.w, sg.w, lb.w, acc.w);
        }
    }

    // bias handled once per b by the s==0 block (all 4 r's)
    if (s == 0) {
        float4 mb = ((const float4*)mu_bias)[tid];
        float4 sgb, lbb;
        if (USE_WS) {
            sgb = ((const float4*)(sig_ws + (size_t)IN_ * OUT_))[tid];
        } else {
            float4 rb = ((const float4*)ro_bias)[tid];
            sgb.x = softplus_f(rb.x);
            sgb.y = softplus_f(rb.y);
            sgb.z = softplus_f(rb.z);
            sgb.w = softplus_f(rb.w);
        }
        lbb.x = A1B - LOG2F(sgb.x);
        lbb.y = A1B - LOG2F(sgb.y);
        lbb.z = A1B - LOG2F(sgb.z);
        lbb.w = A1B - LOG2F(sgb.w);
        const float xv = 1.0f;   // acc += 1 * bias
#pragma unroll
        for (int r = 0; r < R_; ++r) {
            f4 eb = __builtin_nontemporal_load(
                (const f4*)(eps_bias + (size_t)(b * R_ + r) * OUT_) + tid);
            PROC(eb.x, mb.x, sgb.x, lbb.x, acc.x);
            PROC(eb.y, mb.y, sgb.y, lbb.y, acc.y);
            PROC(eb.z, mb.z, sgb.z, lbb.z, acc.z);
            PROC(eb.w, mb.w, sgb.w, lbb.w, acc.w);
        }
    }

    // back to ln domain: sum(log(.5*(g1+g2))) = LN2*(smix2 - nterms)
    const float nterms = 256.0f + ((s == 0) ? 16.0f : 0.0f);
    float smix = (smix2 - nterms) * LN2F;
    float slpw = slpw2 * LN2F;

    // out[b, o] += acc / R  (mean over r folded in-register; summed across s via atomics)
    float* outp = out + (size_t)b * OUT_ + tid * 4;
    atomicAdd(outp + 0, acc.x * 0.25f);
    atomicAdd(outp + 1, acc.y * 0.25f);
    atomicAdd(outp + 2, acc.z * 0.25f);
    atomicAdd(outp + 3, acc.w * 0.25f);

    // block-reduce the two scalar sums, then one atomic pair per block
    for (int off = 32; off > 0; off >>= 1) {
        smix += __shfl_down(smix, off, 64);
        slpw += __shfl_down(slpw, off, 64);
    }
    __shared__ float red[8];
    const int wave = tid >> 6, lane = tid & 63;
    if (lane == 0) { red[wave] = smix; red[4 + wave] = slpw; }
    __syncthreads();
    if (tid == 0) {
        float sm = red[0] + red[1] + red[2] + red[3];
        float sl = red[4] + red[5] + red[6] + red[7];
        atomicAdd(out + B_ * OUT_ + 0, sm * (1.0f / 128.0f));
        atomicAdd(out + B_ * OUT_ + 1, sl * (1.0f / 128.0f));
    }
}

extern "C" void kernel_launch(void* const* d_in, const int* in_sizes, int n_in,
                              void* d_out, int out_size, void* d_ws, size_t ws_size,
                              hipStream_t stream) {
    const float* x       = (const float*)d_in[0];
    const float* mu      = (const float*)d_in[1];
    const float* ro      = (const float*)d_in[2];
    const float* mu_bias = (const float*)d_in[3];
    const float* ro_bias = (const float*)d_in[4];
    const float* eps     = (const float*)d_in[5];
    const float* eps_b   = (const float*)d_in[6];
    float* out = (float*)d_out;

    const bool use_ws = ws_size >= NPRE * sizeof(float);
    float* sig_ws = (float*)d_ws;

    if (use_ws) {
        // precomp also zero-inits out (NPRE/256 = 4100 blocks covers B*OUT+2)
        precomp_kernel<<<(int)((NPRE + 255) / 256), 256, 0, stream>>>(ro, ro_bias, sig_ws, out);
        main_kernel<true><<<B_ * S_, 256, 0, stream>>>(
            x, mu, ro, mu_bias, ro_bias, eps, eps_b, sig_ws, out);
    } else {
        init_kernel<<<(B_ * OUT_ + 2 + 255) / 256, 256, 0, stream>>>(out);
        main_kernel<false><<<B_ * S_, 256, 0, stream>>>(
            x, mu, ro, mu_bias, ro_bias, eps, eps_b, nullptr, out);
    }
}